// Round 8
// baseline (9040.814 us; speedup 1.0000x reference)
//
#include <hip/hip_runtime.h>
#include <hip/hip_bf16.h>
#include <math.h>

typedef __hip_bfloat16 bf16;

#define B_ 32
#define HW_ 784
#define T_ 785
#define TP_ 197
#define C_ 384
#define H_ 8
#define D_ 48
#define FF_ 1536

// ---------------- sizes (elements) ----------------
static constexpr size_t NRES = (size_t)B_ * T_ * C_;   // 9,646,080
static constexpr size_t NX   = (size_t)B_ * HW_ * C_;  // 9,633,792
static constexpr size_t NCLS = (size_t)B_ * C_;        // 12,288
static constexpr size_t NLN1 = (size_t)T_ * C_;        // 301,440
static constexpr size_t NWP  = (size_t)C_ * C_;        // 147,456
static constexpr size_t NLN2 = (size_t)TP_ * C_;       // 75,648
static constexpr size_t NW1  = (size_t)FF_ * C_;       // 589,824
static constexpr size_t NX2  = (size_t)B_ * TP_ * C_;  // 2,420,736
static constexpr size_t NH   = (size_t)B_ * TP_ * FF_; // 9,682,944

// ---------------- arena byte offsets ----------------
static constexpr size_t XF_OFF   = 0;                       // fp32 input copies
static constexpr size_t CLSF_OFF = XF_OFF   + NX   * 4;
static constexpr size_t LN1W_OFF = CLSF_OFF + NCLS * 4;
static constexpr size_t LN1B_OFF = LN1W_OFF + NLN1 * 4;
static constexpr size_t WQF_OFF  = LN1B_OFF + NLN1 * 4;
static constexpr size_t WKF_OFF  = WQF_OFF  + NWP  * 4;
static constexpr size_t WVF_OFF  = WKF_OFF  + NWP  * 4;
static constexpr size_t WOF_OFF  = WVF_OFF  + NWP  * 4;
static constexpr size_t LN2W_OFF = WOF_OFF  + NWP  * 4;
static constexpr size_t LN2B_OFF = LN2W_OFF + NLN2 * 4;
static constexpr size_t W1F_OFF  = LN2B_OFF + NLN2 * 4;
static constexpr size_t W2F_OFF  = W1F_OFF  + NW1  * 4;
static constexpr size_t X1_OFF   = W2F_OFF  + NW1  * 4;     // fp32 LN1(x_in)
static constexpr size_t Q_OFF    = X1_OFF   + NRES * 4;     // fp32 full-width q
static constexpr size_t K_OFF    = Q_OFF    + NRES * 4;
static constexpr size_t V_OFF    = K_OFF    + NRES * 4;
static constexpr size_t ATT_OFF  = V_OFF    + NRES * 4;     // fp32 attn output (pre-Wo)
static constexpr size_t XM_OFF   = ATT_OFF  + NRES * 4;     // fp32 x_mhsa
static constexpr size_t RES_OFF  = XM_OFF   + NRES * 4;     // fp32 x_res1
static constexpr size_t X2N_OFF  = RES_OFF  + NRES * 4;     // fp32 x2n
static constexpr size_t H_OFF    = X2N_OFF  + NX2  * 4;     // fp32 gelu intermediate
static constexpr size_t MU_OFF   = H_OFF    + NH   * 4;     // fp32[32]
static constexpr size_t RS_OFF   = MU_OFF   + 128;          // fp32[32]
static constexpr size_t CID_OFF  = RS_OFF   + 128;          // double[B][C]
static constexpr size_t CAD_OFF  = CID_OFF  + NCLS * 8;     // double[B][HW]
static constexpr size_t PERM_OFF = CAD_OFF  + (size_t)B_ * HW_ * 8; // int[B][196]
static constexpr size_t FLAG_OFF = PERM_OFF + (size_t)B_ * (TP_ - 1) * 4;
static constexpr size_t ARENA_BYTES = FLAG_OFF + 16;

__device__ __align__(256) unsigned char g_arena[ARENA_BYTES];

template <typename Tp>
__device__ __forceinline__ Tp* ap(size_t off) { return (Tp*)(g_arena + off); }

// ---------------- dtype detect: w_ln1 fp32 1.0 = 0x3F800000; bf16 pair = 0x3F803F80
__global__ void detect_kernel(const unsigned* __restrict__ w)
{
    if (threadIdx.x == 0)
        *ap<int>(FLAG_OFF) = (w[0] == 0x3F803F80u) ? 1 : 0;
}

// ---------------- convert input -> fp32 arena copy
__global__ __launch_bounds__(256) void cvt_kernel(
    const void* __restrict__ src, size_t dst_off, size_t n)
{
    size_t i = (size_t)blockIdx.x * 256 + threadIdx.x;
    if (i >= n) return;
    float v = (*ap<int>(FLAG_OFF))
        ? __bfloat162float(((const bf16*)src)[i])
        : ((const float*)src)[i];
    ap<float>(dst_off)[i] = v;
}

__device__ __forceinline__ float xin_val(int b, int t, int c)
{
    return (t == 0) ? ap<float>(CLSF_OFF)[b * C_ + c]
                    : ap<float>(XF_OFF)[((size_t)b * HW_ + (t - 1)) * C_ + c];
}

// ---------------- per-batch plane mean/rstd of x_in (double accumulation)
__global__ __launch_bounds__(256) void stats1_kernel()
{
    const int TC = T_ * C_;
    int b = blockIdx.x, tid = threadIdx.x;
    __shared__ double r1[256], r2[256];
    double s = 0.0, s2 = 0.0;
    for (int e = tid; e < TC; e += 256) {
        int t = e / C_, c = e - t * C_;
        double v = (double)xin_val(b, t, c);
        s += v; s2 += v * v;
    }
    r1[tid] = s; r2[tid] = s2; __syncthreads();
    for (int o = 128; o; o >>= 1) {
        if (tid < o) { r1[tid] += r1[tid + o]; r2[tid] += r2[tid + o]; }
        __syncthreads();
    }
    if (tid == 0) {
        double m = r1[0] / TC;
        double var = r2[0] / TC - m * m;
        ap<float>(MU_OFF)[b] = (float)m;
        ap<float>(RS_OFF)[b] = (float)(1.0 / sqrt(var + 1e-5));
    }
}

// ---------------- x1 = LN1(x_in)
__global__ __launch_bounds__(256) void ln1_apply_kernel()
{
    size_t i = (size_t)blockIdx.x * 256 + threadIdx.x;
    if (i >= NRES) return;
    int b = (int)(i / (T_ * C_));
    int rem = (int)(i - (size_t)b * T_ * C_);
    int t = rem / C_, c = rem - t * C_;
    float v = xin_val(b, t, c);
    ap<float>(X1_OFF)[i] = (v - ap<float>(MU_OFF)[b]) * ap<float>(RS_OFF)[b]
                           * ap<float>(LN1W_OFF)[t * C_ + c]
                           + ap<float>(LN1B_OFF)[t * C_ + c];
}

// ---------------- tiled GEMM: C[m][n] = sum_k A[m][k] * Bf[n][k]  (B ld == K)
// EMODE 0: store fp32 @ c_off
// EMODE 2: store fp32 gelu_exact(acc) @ c_off
// EMODE 3: acc + fp32 X2N resid -> split FP32 store to dout   (d_out is float*!)
template<int EMODE>
__global__ __launch_bounds__(256) void gemm_t(
    size_t a_off, size_t b_off, float* __restrict__ dout, size_t c_off,
    int M, int N, int K)
{
    __shared__ float As[64][17];
    __shared__ float Bs[64][17];
    int bm = blockIdx.x * 64, bn = blockIdx.y * 64;
    int tid = threadIdx.x;
    int lr = tid >> 4, lc = tid & 15;
    float acc[4][4] = {};
    for (int k0 = 0; k0 < K; k0 += 16) {
#pragma unroll
        for (int i = 0; i < 4; i++) {
            int row = lr + i * 16;
            int gm = bm + row;
            As[row][lc] = (gm < M) ? ap<float>(a_off)[(size_t)gm * K + k0 + lc] : 0.f;
            int gn = bn + row;
            Bs[row][lc] = (gn < N) ? ap<float>(b_off)[(size_t)gn * K + k0 + lc] : 0.f;
        }
        __syncthreads();
#pragma unroll
        for (int kk = 0; kk < 16; kk++) {
            float a0[4], b0[4];
            int tr = tid >> 4, tc = tid & 15;
#pragma unroll
            for (int i = 0; i < 4; i++) a0[i] = As[tr * 4 + i][kk];
#pragma unroll
            for (int j = 0; j < 4; j++) b0[j] = Bs[tc * 4 + j][kk];
#pragma unroll
            for (int i = 0; i < 4; i++)
#pragma unroll
                for (int j = 0; j < 4; j++) acc[i][j] += a0[i] * b0[j];
        }
        __syncthreads();
    }
    int tr = tid >> 4, tc = tid & 15;
#pragma unroll
    for (int i = 0; i < 4; i++) {
        int gm = bm + tr * 4 + i;
        if (gm >= M) continue;
#pragma unroll
        for (int j = 0; j < 4; j++) {
            int gn = bn + tc * 4 + j;
            if (gn >= N) continue;
            float v = acc[i][j];
            if (EMODE == 0) {
                ap<float>(c_off)[(size_t)gm * N + gn] = v;
            } else if (EMODE == 2) {
                v = 0.5f * v * (1.f + erff(v * 0.70710678f));
                ap<float>(c_off)[(size_t)gm * N + gn] = v;
            } else {
                v += ap<float>(X2N_OFF)[(size_t)gm * N + gn];
                int b = gm / TP_, t = gm - b * TP_;
                size_t off = (t == 0)
                    ? ((size_t)B_ * (TP_ - 1) * C_ + (size_t)b * C_ + gn)
                    : ((size_t)(b * (TP_ - 1) + (t - 1)) * C_ + gn);
                dout[off] = v;   // FP32 output
            }
        }
    }
}

// ---------------- fused softmax attention; full-width Q/K/V/ATT (stride C_)
#define RQ 8
__global__ __launch_bounds__(256) void attn_kernel()
{
    __shared__ float s[RQ][788];
    __shared__ float qs[RQ][D_];
    __shared__ float red[RQ][4];
    __shared__ float rowm[RQ], rowsum[RQ];
    const float* Q  = ap<float>(Q_OFF);
    const float* Kf = ap<float>(K_OFF);
    const float* Vf = ap<float>(V_OFF);
    float* A        = ap<float>(ATT_OFF);
    int bh = blockIdx.x;
    int b = bh >> 3, h = bh & 7;
    int q0 = blockIdx.y * RQ;
    int tid = threadIdx.x, wave = tid >> 6, lane = tid & 63;
    size_t base = (size_t)b * T_ * C_ + (size_t)h * D_;

    for (int i = tid; i < RQ * D_; i += 256) {
        int r = i / D_, d = i - (i / D_) * D_;
        qs[r][d] = (q0 + r < T_) ? Q[base + (size_t)(q0 + r) * C_ + d] : 0.f;
    }
    __syncthreads();

    const float scale = 0.14433756729740643f; // 1/sqrt(48)
    float pmax[RQ];
#pragma unroll
    for (int r = 0; r < RQ; r++) pmax[r] = -1e30f;
    for (int k = tid; k < T_; k += 256) {
        const float* krow = Kf + base + (size_t)k * C_;
        float kr[D_];
#pragma unroll
        for (int d = 0; d < D_; d++) kr[d] = krow[d];
#pragma unroll
        for (int r = 0; r < RQ; r++) {
            float acc = 0.f;
#pragma unroll
            for (int d = 0; d < D_; d++) acc += qs[r][d] * kr[d];
            acc *= scale;
            s[r][k] = acc;
            pmax[r] = fmaxf(pmax[r], acc);
        }
    }
#pragma unroll
    for (int r = 0; r < RQ; r++) {
        float m = pmax[r];
        for (int o = 32; o; o >>= 1) m = fmaxf(m, __shfl_down(m, o));
        if (lane == 0) red[r][wave] = m;
    }
    __syncthreads();
    if (tid < RQ)
        rowm[tid] = fmaxf(fmaxf(red[tid][0], red[tid][1]), fmaxf(red[tid][2], red[tid][3]));
    __syncthreads();
    float psum[RQ] = {};
    for (int k = tid; k < T_; k += 256) {
#pragma unroll
        for (int r = 0; r < RQ; r++) {
            float p = expf(s[r][k] - rowm[r]);
            s[r][k] = p;
            psum[r] += p;
        }
    }
#pragma unroll
    for (int r = 0; r < RQ; r++) {
        float m = psum[r];
        for (int o = 32; o; o >>= 1) m += __shfl_down(m, o);
        if (lane == 0) red[r][wave] = m;
    }
    __syncthreads();
    if (tid < RQ)
        rowsum[tid] = red[tid][0] + red[tid][1] + red[tid][2] + red[tid][3];
    __syncthreads();

    if (lane < D_) {
        int r0 = wave * 2;
        float o0 = 0.f, o1 = 0.f;
        for (int k = 0; k < T_; k++) {
            float vv = Vf[base + (size_t)k * C_ + lane];
            o0 += s[r0 + 0][k] * vv;
            o1 += s[r0 + 1][k] * vv;
        }
#pragma unroll
        for (int j = 0; j < 2; j++) {
            int t = q0 + r0 + j;
            float ov = (j == 0) ? o0 : o1;
            if (t < T_) A[base + (size_t)t * C_ + lane] = ov / rowsum[r0 + j];
        }
    }
}

// ---------------- RES = x_in + XM
__global__ __launch_bounds__(256) void res1_kernel()
{
    size_t i = (size_t)blockIdx.x * 256 + threadIdx.x;
    if (i >= NRES) return;
    int b = (int)(i / (T_ * C_));
    int rem = (int)(i - (size_t)b * T_ * C_);
    int t = rem / C_, c = rem - t * C_;
    ap<float>(RES_OFF)[i] = xin_val(b, t, c) + ap<float>(XM_OFF)[i];
}

// ---------------- ci = sigmoid(mean_t(x_mhsa))  (double)
__global__ void ci_kernel()
{
    int b = blockIdx.x, c = threadIdx.x;   // 384 threads
    const float* xm = ap<float>(XM_OFF);
    double s = 0.0;
    for (int t = 0; t < T_; t++) s += (double)xm[((size_t)b * T_ + t) * C_ + c];
    s /= (double)T_;
    ap<double>(CID_OFF)[b * C_ + c] = 1.0 / (1.0 + exp(-s));
}

// ---------------- ca[b][n] = dot(res1[b][n+1], ci[b])  (double)
__global__ __launch_bounds__(64) void ca_kernel()
{
    const float* xres1 = ap<float>(RES_OFF);
    const double* ci   = ap<double>(CID_OFF);
    int idx = blockIdx.x;
    int b = idx / HW_, n = idx - b * HW_;
    int lane = threadIdx.x;
    double s = 0.0;
    for (int c = lane; c < C_; c += 64)
        s += (double)xres1[((size_t)b * T_ + 1 + n) * C_ + c] * ci[b * C_ + c];
    for (int o = 32; o; o >>= 1) s += __shfl_down(s, o);
    if (lane == 0) ap<double>(CAD_OFF)[idx] = s;
}

// ---------------- stable ascending rank; keep ranks 588..783 -> perm[0..195]
__global__ __launch_bounds__(256) void rank_kernel()
{
    const double* ca = ap<double>(CAD_OFF);
    int* perm = ap<int>(PERM_OFF);
    int b = blockIdx.x, tid = threadIdx.x;
    __shared__ double cs[HW_];
    for (int i = tid; i < HW_; i += 256) cs[i] = ca[b * HW_ + i];
    __syncthreads();
    for (int i = tid; i < HW_; i += 256) {
        double vi = cs[i];
        int r = 0;
        for (int j = 0; j < HW_; j++) {
            double vj = cs[j];
            r += (vj < vi) || (vj == vi && j < i);
        }
        if (r >= HW_ - TP_ + 1) perm[b * (TP_ - 1) + (r - (HW_ - TP_ + 1))] = i;
    }
}

// ---------------- gather + plane-LN2 -> X2N fp32 (double stats)
__global__ __launch_bounds__(256) void ln2_kernel()
{
    const float* xres1 = ap<float>(RES_OFF);
    const int* perm = ap<int>(PERM_OFF);
    const float* w  = ap<float>(LN2W_OFF);
    const float* bb = ap<float>(LN2B_OFF);
    const int TC = TP_ * C_;
    int b = blockIdx.x, tid = threadIdx.x;
    __shared__ double r1[256], r2[256];
    double s = 0.0, s2 = 0.0;
    for (int e = tid; e < TC; e += 256) {
        int t = e / C_, c = e - t * C_;
        int st = (t == 0) ? 0 : 1 + perm[b * (TP_ - 1) + t - 1];
        double v = (double)xres1[((size_t)b * T_ + st) * C_ + c];
        s += v; s2 += v * v;
    }
    r1[tid] = s; r2[tid] = s2; __syncthreads();
    for (int o = 128; o; o >>= 1) {
        if (tid < o) { r1[tid] += r1[tid + o]; r2[tid] += r2[tid + o]; }
        __syncthreads();
    }
    float mu = (float)(r1[0] / TC);
    double var = r2[0] / TC - (r1[0] / TC) * (r1[0] / TC);
    float rstd = (float)(1.0 / sqrt(var + 1e-5));
    for (int e = tid; e < TC; e += 256) {
        int t = e / C_, c = e - t * C_;
        int st = (t == 0) ? 0 : 1 + perm[b * (TP_ - 1) + t - 1];
        float v = xres1[((size_t)b * T_ + st) * C_ + c];
        ap<float>(X2N_OFF)[(size_t)b * TC + e] = (v - mu) * rstd * w[e] + bb[e];
    }
}

extern "C" void kernel_launch(void* const* d_in, const int* in_sizes, int n_in,
                              void* d_out, int out_size, void* d_ws, size_t ws_size,
                              hipStream_t stream)
{
    float* out = (float*)d_out;   // reference output dtype is float32!
    (void)d_ws; (void)ws_size; (void)in_sizes; (void)n_in; (void)out_size;

    const int M1 = B_ * T_;          // 25120
    const int M2 = B_ * TP_;         // 6304
    const int GM1 = (M1 + 63) / 64;  // 393
    const int GM2 = (M2 + 63) / 64;  // 99

    // 0. dtype detect + fp32 copies of all inputs
    detect_kernel<<<1, 64, 0, stream>>>((const unsigned*)d_in[2]);
    auto cvt = [&](int i, size_t off, size_t n) {
        cvt_kernel<<<(int)((n + 255) / 256), 256, 0, stream>>>(d_in[i], off, n);
    };
    cvt(0, XF_OFF, NX);      cvt(1, CLSF_OFF, NCLS);
    cvt(2, LN1W_OFF, NLN1);  cvt(3, LN1B_OFF, NLN1);
    cvt(4, WQF_OFF, NWP);    cvt(5, WKF_OFF, NWP);
    cvt(6, WVF_OFF, NWP);    cvt(7, WOF_OFF, NWP);
    cvt(8, LN2W_OFF, NLN2);  cvt(9, LN2B_OFF, NLN2);
    cvt(10, W1F_OFF, NW1);   cvt(11, W2F_OFF, NW1);

    // 1. LN1
    stats1_kernel<<<B_, 256, 0, stream>>>();
    ln1_apply_kernel<<<(int)((NRES + 255) / 256), 256, 0, stream>>>();

    // 2. full-width QKV projections
    gemm_t<0><<<dim3(GM1, C_ / 64), 256, 0, stream>>>(X1_OFF, WQF_OFF, nullptr, Q_OFF, M1, C_, C_);
    gemm_t<0><<<dim3(GM1, C_ / 64), 256, 0, stream>>>(X1_OFF, WKF_OFF, nullptr, K_OFF, M1, C_, C_);
    gemm_t<0><<<dim3(GM1, C_ / 64), 256, 0, stream>>>(X1_OFF, WVF_OFF, nullptr, V_OFF, M1, C_, C_);

    // 3. attention -> ATT; output projection -> XM
    attn_kernel<<<dim3(B_ * H_, (T_ + RQ - 1) / RQ), 256, 0, stream>>>();
    gemm_t<0><<<dim3(GM1, C_ / 64), 256, 0, stream>>>(ATT_OFF, WOF_OFF, nullptr, XM_OFF, M1, C_, C_);

    // 4. residual, ci (double), ca (double), rank, LN2
    res1_kernel<<<(int)((NRES + 255) / 256), 256, 0, stream>>>();
    ci_kernel<<<B_, C_, 0, stream>>>();
    ca_kernel<<<B_ * HW_, 64, 0, stream>>>();
    rank_kernel<<<B_, 256, 0, stream>>>();
    ln2_kernel<<<B_, 256, 0, stream>>>();

    // 5. FFN (fp32 throughout; final epilogue: +x2n, split, FP32 store)
    gemm_t<2><<<dim3(GM2, FF_ / 64), 256, 0, stream>>>(X2N_OFF, W1F_OFF, nullptr, H_OFF, M2, FF_, C_);
    gemm_t<3><<<dim3(GM2, C_ / 64), 256, 0, stream>>>(H_OFF, W2F_OFF, out, 0, M2, C_, FF_);
}

// Round 9
// 3375.998 us; speedup vs baseline: 2.6780x; 2.6780x over previous
//
#include <hip/hip_runtime.h>
#include <hip/hip_bf16.h>
#include <math.h>

typedef __hip_bfloat16 bf16;

#define B_ 32
#define HW_ 784
#define T_ 785
#define TP_ 197
#define C_ 384
#define H_ 8
#define D_ 48
#define FF_ 1536
#define CH_ 64   // (b,h) pairs per attention chunk; 4 chunks of 64

// ---------------- sizes (elements) ----------------
static constexpr size_t NRES = (size_t)B_ * T_ * C_;   // 9,646,080
static constexpr size_t NX   = (size_t)B_ * HW_ * C_;  // 9,633,792
static constexpr size_t NCLS = (size_t)B_ * C_;        // 12,288
static constexpr size_t NLN1 = (size_t)T_ * C_;        // 301,440
static constexpr size_t NWP  = (size_t)C_ * C_;        // 147,456
static constexpr size_t NLN2 = (size_t)TP_ * C_;       // 75,648
static constexpr size_t NW1  = (size_t)FF_ * C_;       // 589,824
static constexpr size_t NX2  = (size_t)B_ * TP_ * C_;  // 2,420,736
static constexpr size_t NH   = (size_t)B_ * TP_ * FF_; // 9,682,944

// ---------------- arena byte offsets ----------------
static constexpr size_t XF_OFF   = 0;                       // fp32 input copies
static constexpr size_t CLSF_OFF = XF_OFF   + NX   * 4;
static constexpr size_t LN1W_OFF = CLSF_OFF + NCLS * 4;
static constexpr size_t LN1B_OFF = LN1W_OFF + NLN1 * 4;
static constexpr size_t WQF_OFF  = LN1B_OFF + NLN1 * 4;
static constexpr size_t WKF_OFF  = WQF_OFF  + NWP  * 4;
static constexpr size_t WVF_OFF  = WKF_OFF  + NWP  * 4;
static constexpr size_t WOF_OFF  = WVF_OFF  + NWP  * 4;
static constexpr size_t LN2W_OFF = WOF_OFF  + NWP  * 4;
static constexpr size_t LN2B_OFF = LN2W_OFF + NLN2 * 4;
static constexpr size_t W1F_OFF  = LN2B_OFF + NLN2 * 4;
static constexpr size_t W2F_OFF  = W1F_OFF  + NW1  * 4;
static constexpr size_t X1_OFF   = W2F_OFF  + NW1  * 4;     // fp32 LN1(x_in)
static constexpr size_t Q_OFF    = X1_OFF   + NRES * 4;     // fp32 full-width q
static constexpr size_t K_OFF    = Q_OFF    + NRES * 4;
static constexpr size_t V_OFF    = K_OFF    + NRES * 4;
static constexpr size_t ATT_OFF  = V_OFF    + NRES * 4;     // fp32 attn output (pre-Wo)
static constexpr size_t XM_OFF   = ATT_OFF  + NRES * 4;     // fp32 x_mhsa
static constexpr size_t RES_OFF  = XM_OFF   + NRES * 4;     // fp32 x_res1
static constexpr size_t X2N_OFF  = RES_OFF  + NRES * 4;     // fp32 x2n
static constexpr size_t H_OFF    = X2N_OFF  + NX2  * 4;     // fp32 gelu intermediate
static constexpr size_t MU_OFF   = H_OFF    + NH   * 4;     // fp32[32]
static constexpr size_t RS_OFF   = MU_OFF   + 128;          // fp32[32]
static constexpr size_t CID_OFF  = RS_OFF   + 128;          // double[B][C]
static constexpr size_t CAD_OFF  = CID_OFF  + NCLS * 8;     // double[B][HW]
static constexpr size_t PERM_OFF = CAD_OFF  + (size_t)B_ * HW_ * 8; // int[B][196]
static constexpr size_t FLAG_OFF = PERM_OFF + (size_t)B_ * (TP_ - 1) * 4;
static constexpr size_t S_OFF    = FLAG_OFF + 16;           // fp32 scores, CH_ heads/chunk
static constexpr size_t ARENA_BYTES = S_OFF + (size_t)CH_ * T_ * T_ * 4; // ~563 MB

__device__ __align__(256) unsigned char g_arena[ARENA_BYTES];

template <typename Tp>
__device__ __forceinline__ Tp* ap(size_t off) { return (Tp*)(g_arena + off); }

// ---------------- dtype detect: w_ln1 fp32 1.0 = 0x3F800000; bf16 pair = 0x3F803F80
__global__ void detect_kernel(const unsigned* __restrict__ w)
{
    if (threadIdx.x == 0)
        *ap<int>(FLAG_OFF) = (w[0] == 0x3F803F80u) ? 1 : 0;
}

// ---------------- convert input -> fp32 arena copy
__global__ __launch_bounds__(256) void cvt_kernel(
    const void* __restrict__ src, size_t dst_off, size_t n)
{
    size_t i = (size_t)blockIdx.x * 256 + threadIdx.x;
    if (i >= n) return;
    float v = (*ap<int>(FLAG_OFF))
        ? __bfloat162float(((const bf16*)src)[i])
        : ((const float*)src)[i];
    ap<float>(dst_off)[i] = v;
}

__device__ __forceinline__ float xin_val(int b, int t, int c)
{
    return (t == 0) ? ap<float>(CLSF_OFF)[b * C_ + c]
                    : ap<float>(XF_OFF)[((size_t)b * HW_ + (t - 1)) * C_ + c];
}

// ---------------- per-batch plane mean/rstd of x_in (double accumulation)
__global__ __launch_bounds__(256) void stats1_kernel()
{
    const int TC = T_ * C_;
    int b = blockIdx.x, tid = threadIdx.x;
    __shared__ double r1[256], r2[256];
    double s = 0.0, s2 = 0.0;
    for (int e = tid; e < TC; e += 256) {
        int t = e / C_, c = e - t * C_;
        double v = (double)xin_val(b, t, c);
        s += v; s2 += v * v;
    }
    r1[tid] = s; r2[tid] = s2; __syncthreads();
    for (int o = 128; o; o >>= 1) {
        if (tid < o) { r1[tid] += r1[tid + o]; r2[tid] += r2[tid + o]; }
        __syncthreads();
    }
    if (tid == 0) {
        double m = r1[0] / TC;
        double var = r2[0] / TC - m * m;
        ap<float>(MU_OFF)[b] = (float)m;
        ap<float>(RS_OFF)[b] = (float)(1.0 / sqrt(var + 1e-5));
    }
}

// ---------------- x1 = LN1(x_in)
__global__ __launch_bounds__(256) void ln1_apply_kernel()
{
    size_t i = (size_t)blockIdx.x * 256 + threadIdx.x;
    if (i >= NRES) return;
    int b = (int)(i / (T_ * C_));
    int rem = (int)(i - (size_t)b * T_ * C_);
    int t = rem / C_, c = rem - t * C_;
    float v = xin_val(b, t, c);
    ap<float>(X1_OFF)[i] = (v - ap<float>(MU_OFF)[b]) * ap<float>(RS_OFF)[b]
                           * ap<float>(LN1W_OFF)[t * C_ + c]
                           + ap<float>(LN1B_OFF)[t * C_ + c];
}

// ---------------- tiled GEMM: C[m][n] = sum_k A[m][k] * Bf[n][k]  (B ld == K)
// LDS layout transposed (As2[kk][row]) so fragment reads are ds_read_b128.
// EMODE 0: store fp32 @ c_off
// EMODE 2: store fp32 gelu_exact(acc) @ c_off
// EMODE 3: acc + fp32 X2N resid -> split FP32 store to dout
template<int EMODE>
__global__ __launch_bounds__(256) void gemm_t(
    size_t a_off, size_t b_off, float* __restrict__ dout, size_t c_off,
    int M, int N, int K)
{
    __shared__ float As2[16][68];
    __shared__ float Bs2[16][68];
    int bm = blockIdx.x * 64, bn = blockIdx.y * 64;
    int tid = threadIdx.x;
    int lr = tid >> 4, lc = tid & 15;
    float acc[4][4] = {};
    for (int k0 = 0; k0 < K; k0 += 16) {
#pragma unroll
        for (int i = 0; i < 4; i++) {
            int row = lr + i * 16;
            int gm = bm + row;
            As2[lc][row] = (gm < M) ? ap<float>(a_off)[(size_t)gm * K + k0 + lc] : 0.f;
            int gn = bn + row;
            Bs2[lc][row] = (gn < N) ? ap<float>(b_off)[(size_t)gn * K + k0 + lc] : 0.f;
        }
        __syncthreads();
#pragma unroll
        for (int kk = 0; kk < 16; kk++) {
            float4 a4 = *(const float4*)&As2[kk][lr * 4];
            float4 b4 = *(const float4*)&Bs2[kk][lc * 4];
            float a0[4] = {a4.x, a4.y, a4.z, a4.w};
            float b0[4] = {b4.x, b4.y, b4.z, b4.w};
#pragma unroll
            for (int i = 0; i < 4; i++)
#pragma unroll
                for (int j = 0; j < 4; j++) acc[i][j] += a0[i] * b0[j];
        }
        __syncthreads();
    }
#pragma unroll
    for (int i = 0; i < 4; i++) {
        int gm = bm + lr * 4 + i;
        if (gm >= M) continue;
#pragma unroll
        for (int j = 0; j < 4; j++) {
            int gn = bn + lc * 4 + j;
            if (gn >= N) continue;
            float v = acc[i][j];
            if (EMODE == 0) {
                ap<float>(c_off)[(size_t)gm * N + gn] = v;
            } else if (EMODE == 2) {
                v = 0.5f * v * (1.f + erff(v * 0.70710678f));
                ap<float>(c_off)[(size_t)gm * N + gn] = v;
            } else {
                v += ap<float>(X2N_OFF)[(size_t)gm * N + gn];
                int b = gm / TP_, t = gm - b * TP_;
                size_t off = (t == 0)
                    ? ((size_t)B_ * (TP_ - 1) * C_ + (size_t)b * C_ + gn)
                    : ((size_t)(b * (TP_ - 1) + (t - 1)) * C_ + gn);
                dout[off] = v;   // FP32 output
            }
        }
    }
}

// ---------------- attention step 1: S = scale * Q K^T, batched per (b,h)
__global__ __launch_bounds__(256) void gemm_s(int bh0)
{
    __shared__ float As2[16][68];
    __shared__ float Bs2[16][68];
    const float* Q  = ap<float>(Q_OFF);
    const float* Kf = ap<float>(K_OFF);
    float* S        = ap<float>(S_OFF);
    int lbh = blockIdx.z;
    int bh = bh0 + lbh;
    int b = bh >> 3, h = bh & 7;
    size_t qkb = (size_t)b * T_ * C_ + (size_t)h * D_;
    int m0 = blockIdx.x * 64, n0 = blockIdx.y * 64;
    int tid = threadIdx.x;
    int lr = tid >> 4, lc = tid & 15;
    float acc[4][4] = {};
    for (int k0 = 0; k0 < D_; k0 += 16) {
#pragma unroll
        for (int i = 0; i < 4; i++) {
            int row = lr + i * 16;
            int gm = m0 + row, gn = n0 + row;
            As2[lc][row] = (gm < T_) ? Q[qkb + (size_t)gm * C_ + k0 + lc] : 0.f;
            Bs2[lc][row] = (gn < T_) ? Kf[qkb + (size_t)gn * C_ + k0 + lc] : 0.f;
        }
        __syncthreads();
#pragma unroll
        for (int kk = 0; kk < 16; kk++) {
            float4 a4 = *(const float4*)&As2[kk][lr * 4];
            float4 b4 = *(const float4*)&Bs2[kk][lc * 4];
            float a0[4] = {a4.x, a4.y, a4.z, a4.w};
            float b0[4] = {b4.x, b4.y, b4.z, b4.w};
#pragma unroll
            for (int i = 0; i < 4; i++)
#pragma unroll
                for (int j = 0; j < 4; j++) acc[i][j] += a0[i] * b0[j];
        }
        __syncthreads();
    }
    const float scale = 0.14433756729740643f; // 1/sqrt(48)
#pragma unroll
    for (int i = 0; i < 4; i++) {
        int m = m0 + lr * 4 + i;
        if (m >= T_) continue;
#pragma unroll
        for (int j = 0; j < 4; j++) {
            int n = n0 + lc * 4 + j;
            if (n < T_) S[((size_t)lbh * T_ + m) * T_ + n] = acc[i][j] * scale;
        }
    }
}

// ---------------- attention step 2: row softmax over S (one wave per row)
__global__ __launch_bounds__(256) void softmax_kernel()
{
    float* S = ap<float>(S_OFF);
    int wave = threadIdx.x >> 6, lane = threadIdx.x & 63;
    size_t row = (size_t)blockIdx.x * 4 + wave;   // < CH_*T_
    float* p = S + row * T_;
    float v[13];
    float m = -1e30f;
#pragma unroll
    for (int j = 0; j < 13; j++) {
        int idx = lane + 64 * j;
        v[j] = (idx < T_) ? p[idx] : -1e30f;
        m = fmaxf(m, v[j]);
    }
    for (int o = 32; o; o >>= 1) m = fmaxf(m, __shfl_down(m, o));
    m = __shfl(m, 0);
    float s = 0.f;
#pragma unroll
    for (int j = 0; j < 13; j++) { v[j] = expf(v[j] - m); s += v[j]; }
    for (int o = 32; o; o >>= 1) s += __shfl_down(s, o);
    s = __shfl(s, 0);
    float inv = 1.f / s;
#pragma unroll
    for (int j = 0; j < 13; j++) {
        int idx = lane + 64 * j;
        if (idx < T_) p[idx] = v[j] * inv;
    }
}

// ---------------- attention step 3: O = P V, batched per (b,h); N=48
__global__ __launch_bounds__(256) void gemm_pv(int bh0)
{
    __shared__ float As2[16][68];
    __shared__ float Bs[16][52];
    const float* S  = ap<float>(S_OFF);
    const float* Vf = ap<float>(V_OFF);
    float* A        = ap<float>(ATT_OFF);
    int lbh = blockIdx.y;
    int bh = bh0 + lbh;
    int b = bh >> 3, h = bh & 7;
    size_t vbase = (size_t)b * T_ * C_ + (size_t)h * D_;
    int m0 = blockIdx.x * 64;
    int tid = threadIdx.x;
    int lr = tid >> 4, lc = tid & 15;
    float acc[4][3] = {};
    for (int k0 = 0; k0 < T_; k0 += 16) {
#pragma unroll
        for (int i = 0; i < 4; i++) {
            int row = lr + i * 16;
            int gm = m0 + row, gk = k0 + lc;
            As2[lc][row] = (gm < T_ && gk < T_)
                ? S[((size_t)lbh * T_ + gm) * T_ + gk] : 0.f;
        }
        for (int e = tid; e < 768; e += 256) {
            int kk = e / 48, n = e - kk * 48;
            int gk = k0 + kk;
            Bs[kk][n] = (gk < T_) ? Vf[vbase + (size_t)gk * C_ + n] : 0.f;
        }
        __syncthreads();
#pragma unroll
        for (int kk = 0; kk < 16; kk++) {
            float4 a4 = *(const float4*)&As2[kk][lr * 4];
            float a0[4] = {a4.x, a4.y, a4.z, a4.w};
            float b0 = Bs[kk][lc * 3], b1 = Bs[kk][lc * 3 + 1], b2 = Bs[kk][lc * 3 + 2];
#pragma unroll
            for (int i = 0; i < 4; i++) {
                acc[i][0] += a0[i] * b0;
                acc[i][1] += a0[i] * b1;
                acc[i][2] += a0[i] * b2;
            }
        }
        __syncthreads();
    }
#pragma unroll
    for (int i = 0; i < 4; i++) {
        int m = m0 + lr * 4 + i;
        if (m >= T_) continue;
#pragma unroll
        for (int j = 0; j < 3; j++)
            A[vbase + (size_t)m * C_ + lc * 3 + j] = acc[i][j];
    }
}

// ---------------- RES = x_in + XM
__global__ __launch_bounds__(256) void res1_kernel()
{
    size_t i = (size_t)blockIdx.x * 256 + threadIdx.x;
    if (i >= NRES) return;
    int b = (int)(i / (T_ * C_));
    int rem = (int)(i - (size_t)b * T_ * C_);
    int t = rem / C_, c = rem - t * C_;
    ap<float>(RES_OFF)[i] = xin_val(b, t, c) + ap<float>(XM_OFF)[i];
}

// ---------------- ci = sigmoid(mean_t(x_mhsa))  (double)
__global__ void ci_kernel()
{
    int b = blockIdx.x, c = threadIdx.x;   // 384 threads
    const float* xm = ap<float>(XM_OFF);
    double s = 0.0;
    for (int t = 0; t < T_; t++) s += (double)xm[((size_t)b * T_ + t) * C_ + c];
    s /= (double)T_;
    ap<double>(CID_OFF)[b * C_ + c] = 1.0 / (1.0 + exp(-s));
}

// ---------------- ca[b][n] = dot(res1[b][n+1], ci[b])  (double)
__global__ __launch_bounds__(64) void ca_kernel()
{
    const float* xres1 = ap<float>(RES_OFF);
    const double* ci   = ap<double>(CID_OFF);
    int idx = blockIdx.x;
    int b = idx / HW_, n = idx - b * HW_;
    int lane = threadIdx.x;
    double s = 0.0;
    for (int c = lane; c < C_; c += 64)
        s += (double)xres1[((size_t)b * T_ + 1 + n) * C_ + c] * ci[b * C_ + c];
    for (int o = 32; o; o >>= 1) s += __shfl_down(s, o);
    if (lane == 0) ap<double>(CAD_OFF)[idx] = s;
}

// ---------------- stable ascending rank; keep ranks 588..783 -> perm[0..195]
__global__ __launch_bounds__(256) void rank_kernel()
{
    const double* ca = ap<double>(CAD_OFF);
    int* perm = ap<int>(PERM_OFF);
    int b = blockIdx.x, tid = threadIdx.x;
    __shared__ double cs[HW_];
    for (int i = tid; i < HW_; i += 256) cs[i] = ca[b * HW_ + i];
    __syncthreads();
    for (int i = tid; i < HW_; i += 256) {
        double vi = cs[i];
        int r = 0;
        for (int j = 0; j < HW_; j++) {
            double vj = cs[j];
            r += (vj < vi) || (vj == vi && j < i);
        }
        if (r >= HW_ - TP_ + 1) perm[b * (TP_ - 1) + (r - (HW_ - TP_ + 1))] = i;
    }
}

// ---------------- gather + plane-LN2 -> X2N fp32 (double stats)
__global__ __launch_bounds__(256) void ln2_kernel()
{
    const float* xres1 = ap<float>(RES_OFF);
    const int* perm = ap<int>(PERM_OFF);
    const float* w  = ap<float>(LN2W_OFF);
    const float* bb = ap<float>(LN2B_OFF);
    const int TC = TP_ * C_;
    int b = blockIdx.x, tid = threadIdx.x;
    __shared__ double r1[256], r2[256];
    double s = 0.0, s2 = 0.0;
    for (int e = tid; e < TC; e += 256) {
        int t = e / C_, c = e - t * C_;
        int st = (t == 0) ? 0 : 1 + perm[b * (TP_ - 1) + t - 1];
        double v = (double)xres1[((size_t)b * T_ + st) * C_ + c];
        s += v; s2 += v * v;
    }
    r1[tid] = s; r2[tid] = s2; __syncthreads();
    for (int o = 128; o; o >>= 1) {
        if (tid < o) { r1[tid] += r1[tid + o]; r2[tid] += r2[tid + o]; }
        __syncthreads();
    }
    float mu = (float)(r1[0] / TC);
    double var = r2[0] / TC - (r1[0] / TC) * (r1[0] / TC);
    float rstd = (float)(1.0 / sqrt(var + 1e-5));
    for (int e = tid; e < TC; e += 256) {
        int t = e / C_, c = e - t * C_;
        int st = (t == 0) ? 0 : 1 + perm[b * (TP_ - 1) + t - 1];
        float v = xres1[((size_t)b * T_ + st) * C_ + c];
        ap<float>(X2N_OFF)[(size_t)b * TC + e] = (v - mu) * rstd * w[e] + bb[e];
    }
}

extern "C" void kernel_launch(void* const* d_in, const int* in_sizes, int n_in,
                              void* d_out, int out_size, void* d_ws, size_t ws_size,
                              hipStream_t stream)
{
    float* out = (float*)d_out;   // reference output dtype is float32
    (void)d_ws; (void)ws_size; (void)in_sizes; (void)n_in; (void)out_size;

    const int M1 = B_ * T_;          // 25120
    const int M2 = B_ * TP_;         // 6304
    const int GM1 = (M1 + 63) / 64;  // 393
    const int GM2 = (M2 + 63) / 64;  // 99
    const int GT  = (T_ + 63) / 64;  // 13

    // 0. dtype detect + fp32 copies of all inputs
    detect_kernel<<<1, 64, 0, stream>>>((const unsigned*)d_in[2]);
    auto cvt = [&](int i, size_t off, size_t n) {
        cvt_kernel<<<(int)((n + 255) / 256), 256, 0, stream>>>(d_in[i], off, n);
    };
    cvt(0, XF_OFF, NX);      cvt(1, CLSF_OFF, NCLS);
    cvt(2, LN1W_OFF, NLN1);  cvt(3, LN1B_OFF, NLN1);
    cvt(4, WQF_OFF, NWP);    cvt(5, WKF_OFF, NWP);
    cvt(6, WVF_OFF, NWP);    cvt(7, WOF_OFF, NWP);
    cvt(8, LN2W_OFF, NLN2);  cvt(9, LN2B_OFF, NLN2);
    cvt(10, W1F_OFF, NW1);   cvt(11, W2F_OFF, NW1);

    // 1. LN1
    stats1_kernel<<<B_, 256, 0, stream>>>();
    ln1_apply_kernel<<<(int)((NRES + 255) / 256), 256, 0, stream>>>();

    // 2. full-width QKV projections
    gemm_t<0><<<dim3(GM1, C_ / 64), 256, 0, stream>>>(X1_OFF, WQF_OFF, nullptr, Q_OFF, M1, C_, C_);
    gemm_t<0><<<dim3(GM1, C_ / 64), 256, 0, stream>>>(X1_OFF, WKF_OFF, nullptr, K_OFF, M1, C_, C_);
    gemm_t<0><<<dim3(GM1, C_ / 64), 256, 0, stream>>>(X1_OFF, WVF_OFF, nullptr, V_OFF, M1, C_, C_);

    // 3. attention as batched GEMMs, chunked over CH_ (b,h) pairs for L3 reuse
    for (int bh0 = 0; bh0 < B_ * H_; bh0 += CH_) {
        gemm_s<<<dim3(GT, GT, CH_), 256, 0, stream>>>(bh0);
        softmax_kernel<<<CH_ * T_ / 4 + (CH_ * T_ % 4 ? 1 : 0), 256, 0, stream>>>();
        gemm_pv<<<dim3(GT, CH_), 256, 0, stream>>>(bh0);
    }
    // output projection -> XM
    gemm_t<0><<<dim3(GM1, C_ / 64), 256, 0, stream>>>(ATT_OFF, WOF_OFF, nullptr, XM_OFF, M1, C_, C_);

    // 4. residual, ci (double), ca (double), rank, LN2
    res1_kernel<<<(int)((NRES + 255) / 256), 256, 0, stream>>>();
    ci_kernel<<<B_, C_, 0, stream>>>();
    ca_kernel<<<B_ * HW_, 64, 0, stream>>>();
    rank_kernel<<<B_, 256, 0, stream>>>();
    ln2_kernel<<<B_, 256, 0, stream>>>();

    // 5. FFN (fp32; final epilogue: +x2n, split, FP32 store)
    gemm_t<2><<<dim3(GM2, FF_ / 64), 256, 0, stream>>>(X2N_OFF, W1F_OFF, nullptr, H_OFF, M2, FF_, C_);
    gemm_t<3><<<dim3(GM2, C_ / 64), 256, 0, stream>>>(H_OFF, W2F_OFF, out, 0, M2, C_, FF_);
}

// Round 10
// 2936.583 us; speedup vs baseline: 3.0787x; 1.1496x over previous
//
#include <hip/hip_runtime.h>
#include <hip/hip_bf16.h>
#include <math.h>

typedef __hip_bfloat16 bf16;

#define B_ 32
#define HW_ 784
#define T_ 785
#define TP_ 197
#define C_ 384
#define H_ 8
#define D_ 48
#define FF_ 1536
#define CH_ 64   // (b,h) pairs per attention chunk; 4 chunks of 64

// ---------------- sizes (elements) ----------------
static constexpr size_t NRES = (size_t)B_ * T_ * C_;   // 9,646,080
static constexpr size_t NX   = (size_t)B_ * HW_ * C_;  // 9,633,792
static constexpr size_t NCLS = (size_t)B_ * C_;        // 12,288
static constexpr size_t NLN1 = (size_t)T_ * C_;        // 301,440
static constexpr size_t NWP  = (size_t)C_ * C_;        // 147,456
static constexpr size_t NLN2 = (size_t)TP_ * C_;       // 75,648
static constexpr size_t NW1  = (size_t)FF_ * C_;       // 589,824
static constexpr size_t NX2  = (size_t)B_ * TP_ * C_;  // 2,420,736
static constexpr size_t NH   = (size_t)B_ * TP_ * FF_; // 9,682,944

// ---------------- arena byte offsets ----------------
// NOTE: the 12 fp32 input copies are CONTIGUOUS in input order -> single cvt kernel.
static constexpr size_t XF_OFF   = 0;
static constexpr size_t CLSF_OFF = XF_OFF   + NX   * 4;
static constexpr size_t LN1W_OFF = CLSF_OFF + NCLS * 4;
static constexpr size_t LN1B_OFF = LN1W_OFF + NLN1 * 4;
static constexpr size_t WQF_OFF  = LN1B_OFF + NLN1 * 4;
static constexpr size_t WKF_OFF  = WQF_OFF  + NWP  * 4;
static constexpr size_t WVF_OFF  = WKF_OFF  + NWP  * 4;
static constexpr size_t WOF_OFF  = WVF_OFF  + NWP  * 4;
static constexpr size_t LN2W_OFF = WOF_OFF  + NWP  * 4;
static constexpr size_t LN2B_OFF = LN2W_OFF + NLN2 * 4;
static constexpr size_t W1F_OFF  = LN2B_OFF + NLN2 * 4;
static constexpr size_t W2F_OFF  = W1F_OFF  + NW1  * 4;
static constexpr size_t X1_OFF   = W2F_OFF  + NW1  * 4;     // fp32 LN1(x_in)
static constexpr size_t Q_OFF    = X1_OFF   + NRES * 4;
static constexpr size_t K_OFF    = Q_OFF    + NRES * 4;
static constexpr size_t V_OFF    = K_OFF    + NRES * 4;
static constexpr size_t ATT_OFF  = V_OFF    + NRES * 4;     // attn out (pre-Wo)
static constexpr size_t XM_OFF   = ATT_OFF  + NRES * 4;     // x_mhsa
static constexpr size_t RES_OFF  = XM_OFF   + NRES * 4;     // x_res1
static constexpr size_t X2N_OFF  = RES_OFF  + NRES * 4;     // x2n
static constexpr size_t H_OFF    = X2N_OFF  + NX2  * 4;     // gelu intermediate
static constexpr size_t MU_OFF   = H_OFF    + NH   * 4;     // fp32[32]
static constexpr size_t RS_OFF   = MU_OFF   + 128;          // fp32[32]
static constexpr size_t CID_OFF  = RS_OFF   + 128;          // double[B][C]
static constexpr size_t CAD_OFF  = CID_OFF  + NCLS * 8;     // double[B][HW]
static constexpr size_t PERM_OFF = CAD_OFF  + (size_t)B_ * HW_ * 8; // int[B][196]
static constexpr size_t FLAG_OFF = PERM_OFF + (size_t)B_ * (TP_ - 1) * 4;
static constexpr size_t PS_OFF   = FLAG_OFF + 16;           // double2[32*16] stats partials
static constexpr size_t CIP_OFF  = PS_OFF + 32 * 16 * 16;   // double[B*8][C] ci partials
static constexpr size_t S_OFF    = CIP_OFF + (size_t)B_ * 8 * C_ * 8;
static constexpr size_t ARENA_BYTES = S_OFF + (size_t)CH_ * T_ * T_ * 4; // ~564 MB

__device__ __align__(256) unsigned char g_arena[ARENA_BYTES];

template <typename Tp>
__device__ __forceinline__ Tp* ap(size_t off) { return (Tp*)(g_arena + off); }

// ---------------- dtype detect: w_ln1 fp32 1.0 = 0x3F800000; bf16 pair = 0x3F803F80
__global__ void detect_kernel(const unsigned* __restrict__ w)
{
    if (threadIdx.x == 0)
        *ap<int>(FLAG_OFF) = (w[0] == 0x3F803F80u) ? 1 : 0;
}

// ---------------- single merged convert: all 12 inputs -> contiguous fp32 arena
struct SrcPtrs { const void* p[12]; };
static constexpr size_t SEGB[13] = {
    0,
    NX,
    NX + NCLS,
    NX + NCLS + NLN1,
    NX + NCLS + 2 * NLN1,
    NX + NCLS + 2 * NLN1 + NWP,
    NX + NCLS + 2 * NLN1 + 2 * NWP,
    NX + NCLS + 2 * NLN1 + 3 * NWP,
    NX + NCLS + 2 * NLN1 + 4 * NWP,
    NX + NCLS + 2 * NLN1 + 4 * NWP + NLN2,
    NX + NCLS + 2 * NLN1 + 4 * NWP + 2 * NLN2,
    NX + NCLS + 2 * NLN1 + 4 * NWP + 2 * NLN2 + NW1,
    NX + NCLS + 2 * NLN1 + 4 * NWP + 2 * NLN2 + 2 * NW1,
};
static constexpr size_t NTOT_CVT = SEGB[12];  // 12,169,728

__global__ __launch_bounds__(256) void cvt_all_kernel(SrcPtrs sp)
{
    size_t i = (size_t)blockIdx.x * 256 + threadIdx.x;
    if (i >= NTOT_CVT) return;
    int seg = 0;
#pragma unroll
    for (int k = 1; k < 12; k++) seg += (i >= SEGB[k]);
    size_t li = i - SEGB[seg];
    const void* src = sp.p[seg];
    float v = (*ap<int>(FLAG_OFF))
        ? __bfloat162float(((const bf16*)src)[li])
        : ((const float*)src)[li];
    ap<float>(XF_OFF)[i] = v;   // dst regions are contiguous in segment order
}

__device__ __forceinline__ float xin_val(int b, int t, int c)
{
    return (t == 0) ? ap<float>(CLSF_OFF)[b * C_ + c]
                    : ap<float>(XF_OFF)[((size_t)b * HW_ + (t - 1)) * C_ + c];
}

// ---------------- LN1 stats stage A: 32x16 blocks, fp64 partials
__global__ __launch_bounds__(256) void stats1a_kernel()
{
    const int TC = T_ * C_;             // 301,440
    const int SL = (TC + 15) / 16;      // 18,840
    int b = blockIdx.x, s = blockIdx.y, tid = threadIdx.x;
    int e0 = s * SL, e1 = min(e0 + SL, TC);
    __shared__ double r1[256], r2[256];
    double sm = 0.0, s2 = 0.0;
    for (int e = e0 + tid; e < e1; e += 256) {
        int t = e / C_, c = e - t * C_;
        double v = (double)xin_val(b, t, c);
        sm += v; s2 += v * v;
    }
    r1[tid] = sm; r2[tid] = s2; __syncthreads();
    for (int o = 128; o; o >>= 1) {
        if (tid < o) { r1[tid] += r1[tid + o]; r2[tid] += r2[tid + o]; }
        __syncthreads();
    }
    if (tid == 0) {
        double2* ps = ap<double2>(PS_OFF);
        ps[b * 16 + s] = make_double2(r1[0], r2[0]);
    }
}

// ---------------- LN1 stats stage B: finalize mu/rstd
__global__ __launch_bounds__(64) void stats1b_kernel()
{
    int b = blockIdx.x, lane = threadIdx.x;
    const double2* ps = ap<double2>(PS_OFF);
    double sm = 0.0, s2 = 0.0;
    if (lane < 16) { sm = ps[b * 16 + lane].x; s2 = ps[b * 16 + lane].y; }
    for (int o = 8; o; o >>= 1) { sm += __shfl_down(sm, o); s2 += __shfl_down(s2, o); }
    if (lane == 0) {
        const int TC = T_ * C_;
        double m = sm / TC;
        double var = s2 / TC - m * m;
        ap<float>(MU_OFF)[b] = (float)m;
        ap<float>(RS_OFF)[b] = (float)(1.0 / sqrt(var + 1e-5));
    }
}

// ---------------- x1 = LN1(x_in)
__global__ __launch_bounds__(256) void ln1_apply_kernel()
{
    size_t i = (size_t)blockIdx.x * 256 + threadIdx.x;
    if (i >= NRES) return;
    int b = (int)(i / (T_ * C_));
    int rem = (int)(i - (size_t)b * T_ * C_);
    int t = rem / C_, c = rem - t * C_;
    float v = xin_val(b, t, c);
    ap<float>(X1_OFF)[i] = (v - ap<float>(MU_OFF)[b]) * ap<float>(RS_OFF)[b]
                           * ap<float>(LN1W_OFF)[t * C_ + c]
                           + ap<float>(LN1B_OFF)[t * C_ + c];
}

// ---------------- tiled GEMM: C[m][n] = sum_k A[m][k] * Bf[n][k]  (B ld == K)
// EMODE 0: store fp32 @ c_off
// EMODE 2: store fp32 gelu_exact(acc) @ c_off
// EMODE 3: acc + fp32 X2N resid -> split FP32 store to dout
// EMODE 4: store acc @ c_off (XM) AND acc + x_in -> RES  (fused Wo + residual)
template<int EMODE>
__global__ __launch_bounds__(256) void gemm_t(
    size_t a_off, size_t b_off, float* __restrict__ dout, size_t c_off,
    int M, int N, int K)
{
    __shared__ float As2[16][68];
    __shared__ float Bs2[16][68];
    int bm = blockIdx.x * 64, bn = blockIdx.y * 64;
    int tid = threadIdx.x;
    int lr = tid >> 4, lc = tid & 15;
    float acc[4][4] = {};
    for (int k0 = 0; k0 < K; k0 += 16) {
#pragma unroll
        for (int i = 0; i < 4; i++) {
            int row = lr + i * 16;
            int gm = bm + row;
            As2[lc][row] = (gm < M) ? ap<float>(a_off)[(size_t)gm * K + k0 + lc] : 0.f;
            int gn = bn + row;
            Bs2[lc][row] = (gn < N) ? ap<float>(b_off)[(size_t)gn * K + k0 + lc] : 0.f;
        }
        __syncthreads();
#pragma unroll
        for (int kk = 0; kk < 16; kk++) {
            float4 a4 = *(const float4*)&As2[kk][lr * 4];
            float4 b4 = *(const float4*)&Bs2[kk][lc * 4];
            float a0[4] = {a4.x, a4.y, a4.z, a4.w};
            float b0[4] = {b4.x, b4.y, b4.z, b4.w};
#pragma unroll
            for (int i = 0; i < 4; i++)
#pragma unroll
                for (int j = 0; j < 4; j++) acc[i][j] += a0[i] * b0[j];
        }
        __syncthreads();
    }
#pragma unroll
    for (int i = 0; i < 4; i++) {
        int gm = bm + lr * 4 + i;
        if (gm >= M) continue;
#pragma unroll
        for (int j = 0; j < 4; j++) {
            int gn = bn + lc * 4 + j;
            if (gn >= N) continue;
            float v = acc[i][j];
            size_t idx = (size_t)gm * N + gn;
            if (EMODE == 0) {
                ap<float>(c_off)[idx] = v;
            } else if (EMODE == 2) {
                v = 0.5f * v * (1.f + erff(v * 0.70710678f));
                ap<float>(c_off)[idx] = v;
            } else if (EMODE == 4) {
                ap<float>(c_off)[idx] = v;   // XM
                int b = gm / T_, t = gm - b * T_;
                ap<float>(RES_OFF)[idx] = v + xin_val(b, t, gn);
            } else {
                v += ap<float>(X2N_OFF)[idx];
                int b = gm / TP_, t = gm - b * TP_;
                size_t off = (t == 0)
                    ? ((size_t)B_ * (TP_ - 1) * C_ + (size_t)b * C_ + gn)
                    : ((size_t)(b * (TP_ - 1) + (t - 1)) * C_ + gn);
                dout[off] = v;   // FP32 output
            }
        }
    }
}

// ---------------- attention step 1: S = scale * Q K^T, batched per (b,h)
__global__ __launch_bounds__(256) void gemm_s(int bh0)
{
    __shared__ float As2[16][68];
    __shared__ float Bs2[16][68];
    const float* Q  = ap<float>(Q_OFF);
    const float* Kf = ap<float>(K_OFF);
    float* S        = ap<float>(S_OFF);
    int lbh = blockIdx.z;
    int bh = bh0 + lbh;
    int b = bh >> 3, h = bh & 7;
    size_t qkb = (size_t)b * T_ * C_ + (size_t)h * D_;
    int m0 = blockIdx.x * 64, n0 = blockIdx.y * 64;
    int tid = threadIdx.x;
    int lr = tid >> 4, lc = tid & 15;
    float acc[4][4] = {};
    for (int k0 = 0; k0 < D_; k0 += 16) {
#pragma unroll
        for (int i = 0; i < 4; i++) {
            int row = lr + i * 16;
            int gm = m0 + row, gn = n0 + row;
            As2[lc][row] = (gm < T_) ? Q[qkb + (size_t)gm * C_ + k0 + lc] : 0.f;
            Bs2[lc][row] = (gn < T_) ? Kf[qkb + (size_t)gn * C_ + k0 + lc] : 0.f;
        }
        __syncthreads();
#pragma unroll
        for (int kk = 0; kk < 16; kk++) {
            float4 a4 = *(const float4*)&As2[kk][lr * 4];
            float4 b4 = *(const float4*)&Bs2[kk][lc * 4];
            float a0[4] = {a4.x, a4.y, a4.z, a4.w};
            float b0[4] = {b4.x, b4.y, b4.z, b4.w};
#pragma unroll
            for (int i = 0; i < 4; i++)
#pragma unroll
                for (int j = 0; j < 4; j++) acc[i][j] += a0[i] * b0[j];
        }
        __syncthreads();
    }
    const float scale = 0.14433756729740643f; // 1/sqrt(48)
#pragma unroll
    for (int i = 0; i < 4; i++) {
        int m = m0 + lr * 4 + i;
        if (m >= T_) continue;
#pragma unroll
        for (int j = 0; j < 4; j++) {
            int n = n0 + lc * 4 + j;
            if (n < T_) S[((size_t)lbh * T_ + m) * T_ + n] = acc[i][j] * scale;
        }
    }
}

// ---------------- attention step 2: row softmax over S (one wave per row)
__global__ __launch_bounds__(256) void softmax_kernel()
{
    float* S = ap<float>(S_OFF);
    int wave = threadIdx.x >> 6, lane = threadIdx.x & 63;
    size_t row = (size_t)blockIdx.x * 4 + wave;   // < CH_*T_
    float* p = S + row * T_;
    float v[13];
    float m = -1e30f;
#pragma unroll
    for (int j = 0; j < 13; j++) {
        int idx = lane + 64 * j;
        v[j] = (idx < T_) ? p[idx] : -1e30f;
        m = fmaxf(m, v[j]);
    }
    for (int o = 32; o; o >>= 1) m = fmaxf(m, __shfl_down(m, o));
    m = __shfl(m, 0);
    float s = 0.f;
#pragma unroll
    for (int j = 0; j < 13; j++) { v[j] = expf(v[j] - m); s += v[j]; }
    for (int o = 32; o; o >>= 1) s += __shfl_down(s, o);
    s = __shfl(s, 0);
    float inv = 1.f / s;
#pragma unroll
    for (int j = 0; j < 13; j++) {
        int idx = lane + 64 * j;
        if (idx < T_) p[idx] = v[j] * inv;
    }
}

// ---------------- attention step 3: O = P V, batched per (b,h); N=48
__global__ __launch_bounds__(256) void gemm_pv(int bh0)
{
    __shared__ float As2[16][68];
    __shared__ float Bs[16][52];
    const float* S  = ap<float>(S_OFF);
    const float* Vf = ap<float>(V_OFF);
    float* A        = ap<float>(ATT_OFF);
    int lbh = blockIdx.y;
    int bh = bh0 + lbh;
    int b = bh >> 3, h = bh & 7;
    size_t vbase = (size_t)b * T_ * C_ + (size_t)h * D_;
    int m0 = blockIdx.x * 64;
    int tid = threadIdx.x;
    int lr = tid >> 4, lc = tid & 15;
    float acc[4][3] = {};
    for (int k0 = 0; k0 < T_; k0 += 16) {
#pragma unroll
        for (int i = 0; i < 4; i++) {
            int row = lr + i * 16;
            int gm = m0 + row, gk = k0 + lc;
            As2[lc][row] = (gm < T_ && gk < T_)
                ? S[((size_t)lbh * T_ + gm) * T_ + gk] : 0.f;
        }
        for (int e = tid; e < 768; e += 256) {
            int kk = e / 48, n = e - kk * 48;
            int gk = k0 + kk;
            Bs[kk][n] = (gk < T_) ? Vf[vbase + (size_t)gk * C_ + n] : 0.f;
        }
        __syncthreads();
#pragma unroll
        for (int kk = 0; kk < 16; kk++) {
            float4 a4 = *(const float4*)&As2[kk][lr * 4];
            float a0[4] = {a4.x, a4.y, a4.z, a4.w};
            float b0 = Bs[kk][lc * 3], b1 = Bs[kk][lc * 3 + 1], b2 = Bs[kk][lc * 3 + 2];
#pragma unroll
            for (int i = 0; i < 4; i++) {
                acc[i][0] += a0[i] * b0;
                acc[i][1] += a0[i] * b1;
                acc[i][2] += a0[i] * b2;
            }
        }
        __syncthreads();
    }
#pragma unroll
    for (int i = 0; i < 4; i++) {
        int m = m0 + lr * 4 + i;
        if (m >= T_) continue;
#pragma unroll
        for (int j = 0; j < 3; j++)
            A[vbase + (size_t)m * C_ + lc * 3 + j] = acc[i][j];
    }
}

// ---------------- ci stage A: partial column sums of XM over t-slices (double)
__global__ __launch_bounds__(384) void cia_kernel()
{
    int b = blockIdx.x, s = blockIdx.y, c = threadIdx.x;
    const float* xm = ap<float>(XM_OFF);
    const int SL = (T_ + 7) / 8;   // 99
    int t0 = s * SL, t1 = min(t0 + SL, T_);
    double sm = 0.0;
    for (int t = t0; t < t1; t++) sm += (double)xm[((size_t)b * T_ + t) * C_ + c];
    ap<double>(CIP_OFF)[((size_t)b * 8 + s) * C_ + c] = sm;
}

// ---------------- ci stage B: sum 8 partials, sigmoid (double)
__global__ __launch_bounds__(384) void cib_kernel()
{
    int b = blockIdx.x, c = threadIdx.x;
    const double* pp = ap<double>(CIP_OFF);
    double sm = 0.0;
#pragma unroll
    for (int s = 0; s < 8; s++) sm += pp[((size_t)b * 8 + s) * C_ + c];
    sm /= (double)T_;
    ap<double>(CID_OFF)[b * C_ + c] = 1.0 / (1.0 + exp(-sm));
}

// ---------------- ca[b][n] = dot(res1[b][n+1], ci[b])  (double)
__global__ __launch_bounds__(64) void ca_kernel()
{
    const float* xres1 = ap<float>(RES_OFF);
    const double* ci   = ap<double>(CID_OFF);
    int idx = blockIdx.x;
    int b = idx / HW_, n = idx - b * HW_;
    int lane = threadIdx.x;
    double s = 0.0;
    for (int c = lane; c < C_; c += 64)
        s += (double)xres1[((size_t)b * T_ + 1 + n) * C_ + c] * ci[b * C_ + c];
    for (int o = 32; o; o >>= 1) s += __shfl_down(s, o);
    if (lane == 0) ap<double>(CAD_OFF)[idx] = s;
}

// ---------------- stable ascending rank; keep ranks 588..783 -> perm[0..195]
__global__ __launch_bounds__(256) void rank_kernel()
{
    const double* ca = ap<double>(CAD_OFF);
    int* perm = ap<int>(PERM_OFF);
    int b = blockIdx.x, tid = threadIdx.x;
    __shared__ double cs[HW_];
    for (int i = tid; i < HW_; i += 256) cs[i] = ca[b * HW_ + i];
    __syncthreads();
    for (int i = tid; i < HW_; i += 256) {
        double vi = cs[i];
        int r = 0;
        for (int j = 0; j < HW_; j++) {
            double vj = cs[j];
            r += (vj < vi) || (vj == vi && j < i);
        }
        if (r >= HW_ - TP_ + 1) perm[b * (TP_ - 1) + (r - (HW_ - TP_ + 1))] = i;
    }
}

// ---------------- gather + plane-LN2 -> X2N fp32 (double stats)
__global__ __launch_bounds__(256) void ln2_kernel()
{
    const float* xres1 = ap<float>(RES_OFF);
    const int* perm = ap<int>(PERM_OFF);
    const float* w  = ap<float>(LN2W_OFF);
    const float* bb = ap<float>(LN2B_OFF);
    const int TC = TP_ * C_;
    int b = blockIdx.x, tid = threadIdx.x;
    __shared__ double r1[256], r2[256];
    double s = 0.0, s2 = 0.0;
    for (int e = tid; e < TC; e += 256) {
        int t = e / C_, c = e - t * C_;
        int st = (t == 0) ? 0 : 1 + perm[b * (TP_ - 1) + t - 1];
        double v = (double)xres1[((size_t)b * T_ + st) * C_ + c];
        s += v; s2 += v * v;
    }
    r1[tid] = s; r2[tid] = s2; __syncthreads();
    for (int o = 128; o; o >>= 1) {
        if (tid < o) { r1[tid] += r1[tid + o]; r2[tid] += r2[tid + o]; }
        __syncthreads();
    }
    float mu = (float)(r1[0] / TC);
    double var = r2[0] / TC - (r1[0] / TC) * (r1[0] / TC);
    float rstd = (float)(1.0 / sqrt(var + 1e-5));
    for (int e = tid; e < TC; e += 256) {
        int t = e / C_, c = e - t * C_;
        int st = (t == 0) ? 0 : 1 + perm[b * (TP_ - 1) + t - 1];
        float v = xres1[((size_t)b * T_ + st) * C_ + c];
        ap<float>(X2N_OFF)[(size_t)b * TC + e] = (v - mu) * rstd * w[e] + bb[e];
    }
}

extern "C" void kernel_launch(void* const* d_in, const int* in_sizes, int n_in,
                              void* d_out, int out_size, void* d_ws, size_t ws_size,
                              hipStream_t stream)
{
    float* out = (float*)d_out;   // reference output dtype is float32
    (void)d_ws; (void)ws_size; (void)in_sizes; (void)n_in; (void)out_size;

    const int M1 = B_ * T_;          // 25120
    const int M2 = B_ * TP_;         // 6304
    const int GM1 = (M1 + 63) / 64;  // 393
    const int GM2 = (M2 + 63) / 64;  // 99
    const int GT  = (T_ + 63) / 64;  // 13

    // 0. dtype detect + single merged fp32 conversion of all 12 inputs
    detect_kernel<<<1, 64, 0, stream>>>((const unsigned*)d_in[2]);
    SrcPtrs sp;
    for (int i = 0; i < 12; i++) sp.p[i] = d_in[i];
    cvt_all_kernel<<<(int)((NTOT_CVT + 255) / 256), 256, 0, stream>>>(sp);

    // 1. LN1 (two-stage stats, then apply)
    stats1a_kernel<<<dim3(B_, 16), 256, 0, stream>>>();
    stats1b_kernel<<<B_, 64, 0, stream>>>();
    ln1_apply_kernel<<<(int)((NRES + 255) / 256), 256, 0, stream>>>();

    // 2. full-width QKV projections
    gemm_t<0><<<dim3(GM1, C_ / 64), 256, 0, stream>>>(X1_OFF, WQF_OFF, nullptr, Q_OFF, M1, C_, C_);
    gemm_t<0><<<dim3(GM1, C_ / 64), 256, 0, stream>>>(X1_OFF, WKF_OFF, nullptr, K_OFF, M1, C_, C_);
    gemm_t<0><<<dim3(GM1, C_ / 64), 256, 0, stream>>>(X1_OFF, WVF_OFF, nullptr, V_OFF, M1, C_, C_);

    // 3. attention as batched GEMMs, chunked over CH_ (b,h) pairs for L3 reuse
    for (int bh0 = 0; bh0 < B_ * H_; bh0 += CH_) {
        gemm_s<<<dim3(GT, GT, CH_), 256, 0, stream>>>(bh0);
        softmax_kernel<<<CH_ * T_ / 4 + (CH_ * T_ % 4 ? 1 : 0), 256, 0, stream>>>();
        gemm_pv<<<dim3(GT, CH_), 256, 0, stream>>>(bh0);
    }
    // output projection -> XM, fused with residual -> RES
    gemm_t<4><<<dim3(GM1, C_ / 64), 256, 0, stream>>>(ATT_OFF, WOF_OFF, nullptr, XM_OFF, M1, C_, C_);

    // 4. ci (two-stage, double), ca (double), rank, LN2
    cia_kernel<<<dim3(B_, 8), 384, 0, stream>>>();
    cib_kernel<<<B_, 384, 0, stream>>>();
    ca_kernel<<<B_ * HW_, 64, 0, stream>>>();
    rank_kernel<<<B_, 256, 0, stream>>>();
    ln2_kernel<<<B_, 256, 0, stream>>>();

    // 5. FFN (fp32; final epilogue: +x2n, split, FP32 store)
    gemm_t<2><<<dim3(GM2, FF_ / 64), 256, 0, stream>>>(X2N_OFF, W1F_OFF, nullptr, H_OFF, M2, FF_, C_);
    gemm_t<3><<<dim3(GM2, C_ / 64), 256, 0, stream>>>(H_OFF, W2F_OFF, out, 0, M2, C_, FF_);
}

// Round 11
// 2630.271 us; speedup vs baseline: 3.4372x; 1.1165x over previous
//
#include <hip/hip_runtime.h>
#include <hip/hip_bf16.h>
#include <math.h>

typedef __hip_bfloat16 bf16;

#define B_ 32
#define HW_ 784
#define T_ 785
#define TP_ 197
#define C_ 384
#define H_ 8
#define D_ 48
#define FF_ 1536
#define CH_ 64   // (b,h) pairs per attention chunk; 4 chunks of 64

// ---------------- sizes (elements) ----------------
static constexpr size_t NRES = (size_t)B_ * T_ * C_;   // 9,646,080
static constexpr size_t NX   = (size_t)B_ * HW_ * C_;  // 9,633,792
static constexpr size_t NCLS = (size_t)B_ * C_;        // 12,288
static constexpr size_t NLN1 = (size_t)T_ * C_;        // 301,440
static constexpr size_t NWP  = (size_t)C_ * C_;        // 147,456
static constexpr size_t NLN2 = (size_t)TP_ * C_;       // 75,648
static constexpr size_t NW1  = (size_t)FF_ * C_;       // 589,824
static constexpr size_t NX2  = (size_t)B_ * TP_ * C_;  // 2,420,736
static constexpr size_t NH   = (size_t)B_ * TP_ * FF_; // 9,682,944

// ---------------- arena byte offsets ----------------
static constexpr size_t XF_OFF   = 0;
static constexpr size_t CLSF_OFF = XF_OFF   + NX   * 4;
static constexpr size_t LN1W_OFF = CLSF_OFF + NCLS * 4;
static constexpr size_t LN1B_OFF = LN1W_OFF + NLN1 * 4;
static constexpr size_t WQF_OFF  = LN1B_OFF + NLN1 * 4;
static constexpr size_t WKF_OFF  = WQF_OFF  + NWP  * 4;
static constexpr size_t WVF_OFF  = WKF_OFF  + NWP  * 4;
static constexpr size_t WOF_OFF  = WVF_OFF  + NWP  * 4;
static constexpr size_t LN2W_OFF = WOF_OFF  + NWP  * 4;
static constexpr size_t LN2B_OFF = LN2W_OFF + NLN2 * 4;
static constexpr size_t W1F_OFF  = LN2B_OFF + NLN2 * 4;
static constexpr size_t W2F_OFF  = W1F_OFF  + NW1  * 4;
static constexpr size_t X1_OFF   = W2F_OFF  + NW1  * 4;     // fp32 LN1(x_in)
static constexpr size_t Q_OFF    = X1_OFF   + NRES * 4;
static constexpr size_t K_OFF    = Q_OFF    + NRES * 4;
static constexpr size_t V_OFF    = K_OFF    + NRES * 4;
static constexpr size_t ATT_OFF  = V_OFF    + NRES * 4;     // attn out (pre-Wo)
static constexpr size_t XM_OFF   = ATT_OFF  + NRES * 4;     // x_mhsa
static constexpr size_t RES_OFF  = XM_OFF   + NRES * 4;     // x_res1
static constexpr size_t X2N_OFF  = RES_OFF  + NRES * 4;     // x2n
static constexpr size_t H_OFF    = X2N_OFF  + NX2  * 4;     // gelu intermediate
static constexpr size_t MU_OFF   = H_OFF    + NH   * 4;     // fp32[32]
static constexpr size_t RS_OFF   = MU_OFF   + 128;          // fp32[32]
static constexpr size_t CID_OFF  = RS_OFF   + 128;          // double[B][C]
static constexpr size_t CAD_OFF  = CID_OFF  + NCLS * 8;     // double[B][HW]
static constexpr size_t PERM_OFF = CAD_OFF  + (size_t)B_ * HW_ * 8; // int[B][196]
static constexpr size_t FLAG_OFF = PERM_OFF + (size_t)B_ * (TP_ - 1) * 4;
static constexpr size_t PS_OFF   = FLAG_OFF + 16;           // double2[32*16] stats partials
static constexpr size_t CIP_OFF  = PS_OFF + 32 * 16 * 16;   // double[B*8][C] ci partials
static constexpr size_t L2PS_OFF = CIP_OFF + (size_t)B_ * 8 * C_ * 8; // double2[32*8] ln2 partials
static constexpr size_t L2MU_OFF = L2PS_OFF + 32 * 8 * 16;  // fp32[32]
static constexpr size_t L2RS_OFF = L2MU_OFF + 128;          // fp32[32]
static constexpr size_t S_OFF    = L2RS_OFF + 128;
static constexpr size_t ARENA_BYTES = S_OFF + (size_t)CH_ * T_ * T_ * 4; // ~564 MB

__device__ __align__(256) unsigned char g_arena[ARENA_BYTES];

template <typename Tp>
__device__ __forceinline__ Tp* ap(size_t off) { return (Tp*)(g_arena + off); }

// ---------------- dtype detect
__global__ void detect_kernel(const unsigned* __restrict__ w)
{
    if (threadIdx.x == 0)
        *ap<int>(FLAG_OFF) = (w[0] == 0x3F803F80u) ? 1 : 0;
}

// ---------------- single merged convert: all 12 inputs -> contiguous fp32 arena
struct SrcPtrs { const void* p[12]; };
static constexpr size_t SEGB[13] = {
    0,
    NX,
    NX + NCLS,
    NX + NCLS + NLN1,
    NX + NCLS + 2 * NLN1,
    NX + NCLS + 2 * NLN1 + NWP,
    NX + NCLS + 2 * NLN1 + 2 * NWP,
    NX + NCLS + 2 * NLN1 + 3 * NWP,
    NX + NCLS + 2 * NLN1 + 4 * NWP,
    NX + NCLS + 2 * NLN1 + 4 * NWP + NLN2,
    NX + NCLS + 2 * NLN1 + 4 * NWP + 2 * NLN2,
    NX + NCLS + 2 * NLN1 + 4 * NWP + 2 * NLN2 + NW1,
    NX + NCLS + 2 * NLN1 + 4 * NWP + 2 * NLN2 + 2 * NW1,
};
static constexpr size_t NTOT_CVT = SEGB[12];  // 12,169,728

__global__ __launch_bounds__(256) void cvt_all_kernel(SrcPtrs sp)
{
    size_t i = (size_t)blockIdx.x * 256 + threadIdx.x;
    if (i >= NTOT_CVT) return;
    int seg = 0;
#pragma unroll
    for (int k = 1; k < 12; k++) seg += (i >= SEGB[k]);
    size_t li = i - SEGB[seg];
    const void* src = sp.p[seg];
    float v = (*ap<int>(FLAG_OFF))
        ? __bfloat162float(((const bf16*)src)[li])
        : ((const float*)src)[li];
    ap<float>(XF_OFF)[i] = v;
}

__device__ __forceinline__ float xin_val(int b, int t, int c)
{
    return (t == 0) ? ap<float>(CLSF_OFF)[b * C_ + c]
                    : ap<float>(XF_OFF)[((size_t)b * HW_ + (t - 1)) * C_ + c];
}

// ---------------- LN1 stats stage A: 32x16 blocks, fp64 partials
__global__ __launch_bounds__(256) void stats1a_kernel()
{
    const int TC = T_ * C_;
    const int SL = (TC + 15) / 16;
    int b = blockIdx.x, s = blockIdx.y, tid = threadIdx.x;
    int e0 = s * SL, e1 = min(e0 + SL, TC);
    __shared__ double r1[256], r2[256];
    double sm = 0.0, s2 = 0.0;
    for (int e = e0 + tid; e < e1; e += 256) {
        int t = e / C_, c = e - t * C_;
        double v = (double)xin_val(b, t, c);
        sm += v; s2 += v * v;
    }
    r1[tid] = sm; r2[tid] = s2; __syncthreads();
    for (int o = 128; o; o >>= 1) {
        if (tid < o) { r1[tid] += r1[tid + o]; r2[tid] += r2[tid + o]; }
        __syncthreads();
    }
    if (tid == 0) {
        double2* ps = ap<double2>(PS_OFF);
        ps[b * 16 + s] = make_double2(r1[0], r2[0]);
    }
}

// ---------------- LN1 stats stage B
__global__ __launch_bounds__(64) void stats1b_kernel()
{
    int b = blockIdx.x, lane = threadIdx.x;
    const double2* ps = ap<double2>(PS_OFF);
    double sm = 0.0, s2 = 0.0;
    if (lane < 16) { sm = ps[b * 16 + lane].x; s2 = ps[b * 16 + lane].y; }
    for (int o = 8; o; o >>= 1) { sm += __shfl_down(sm, o); s2 += __shfl_down(s2, o); }
    if (lane == 0) {
        const int TC = T_ * C_;
        double m = sm / TC;
        double var = s2 / TC - m * m;
        ap<float>(MU_OFF)[b] = (float)m;
        ap<float>(RS_OFF)[b] = (float)(1.0 / sqrt(var + 1e-5));
    }
}

// ---------------- x1 = LN1(x_in)
__global__ __launch_bounds__(256) void ln1_apply_kernel()
{
    size_t i = (size_t)blockIdx.x * 256 + threadIdx.x;
    if (i >= NRES) return;
    int b = (int)(i / (T_ * C_));
    int rem = (int)(i - (size_t)b * T_ * C_);
    int t = rem / C_, c = rem - t * C_;
    float v = xin_val(b, t, c);
    ap<float>(X1_OFF)[i] = (v - ap<float>(MU_OFF)[b]) * ap<float>(RS_OFF)[b]
                           * ap<float>(LN1W_OFF)[t * C_ + c]
                           + ap<float>(LN1B_OFF)[t * C_ + c];
}

// ---------------- tiled GEMM (B ld == K)
// EMODE 0: store fp32; 2: gelu; 3: +X2N -> split out; 4: XM + RES=acc+x_in
template<int EMODE>
__global__ __launch_bounds__(256) void gemm_t(
    size_t a_off, size_t b_off, float* __restrict__ dout, size_t c_off,
    int M, int N, int K)
{
    __shared__ float As2[16][68];
    __shared__ float Bs2[16][68];
    int bm = blockIdx.x * 64, bn = blockIdx.y * 64;
    int tid = threadIdx.x;
    int lr = tid >> 4, lc = tid & 15;
    float acc[4][4] = {};
    for (int k0 = 0; k0 < K; k0 += 16) {
#pragma unroll
        for (int i = 0; i < 4; i++) {
            int row = lr + i * 16;
            int gm = bm + row;
            As2[lc][row] = (gm < M) ? ap<float>(a_off)[(size_t)gm * K + k0 + lc] : 0.f;
            int gn = bn + row;
            Bs2[lc][row] = (gn < N) ? ap<float>(b_off)[(size_t)gn * K + k0 + lc] : 0.f;
        }
        __syncthreads();
#pragma unroll
        for (int kk = 0; kk < 16; kk++) {
            float4 a4 = *(const float4*)&As2[kk][lr * 4];
            float4 b4 = *(const float4*)&Bs2[kk][lc * 4];
            float a0[4] = {a4.x, a4.y, a4.z, a4.w};
            float b0[4] = {b4.x, b4.y, b4.z, b4.w};
#pragma unroll
            for (int i = 0; i < 4; i++)
#pragma unroll
                for (int j = 0; j < 4; j++) acc[i][j] += a0[i] * b0[j];
        }
        __syncthreads();
    }
#pragma unroll
    for (int i = 0; i < 4; i++) {
        int gm = bm + lr * 4 + i;
        if (gm >= M) continue;
#pragma unroll
        for (int j = 0; j < 4; j++) {
            int gn = bn + lc * 4 + j;
            if (gn >= N) continue;
            float v = acc[i][j];
            size_t idx = (size_t)gm * N + gn;
            if (EMODE == 0) {
                ap<float>(c_off)[idx] = v;
            } else if (EMODE == 2) {
                v = 0.5f * v * (1.f + erff(v * 0.70710678f));
                ap<float>(c_off)[idx] = v;
            } else if (EMODE == 4) {
                ap<float>(c_off)[idx] = v;   // XM
                int b = gm / T_, t = gm - b * T_;
                ap<float>(RES_OFF)[idx] = v + xin_val(b, t, gn);
            } else {
                v += ap<float>(X2N_OFF)[idx];
                int b = gm / TP_, t = gm - b * TP_;
                size_t off = (t == 0)
                    ? ((size_t)B_ * (TP_ - 1) * C_ + (size_t)b * C_ + gn)
                    : ((size_t)(b * (TP_ - 1) + (t - 1)) * C_ + gn);
                dout[off] = v;
            }
        }
    }
}

// ---------------- attention step 1: S = scale * Q K^T
__global__ __launch_bounds__(256) void gemm_s(int bh0)
{
    __shared__ float As2[16][68];
    __shared__ float Bs2[16][68];
    const float* Q  = ap<float>(Q_OFF);
    const float* Kf = ap<float>(K_OFF);
    float* S        = ap<float>(S_OFF);
    int lbh = blockIdx.z;
    int bh = bh0 + lbh;
    int b = bh >> 3, h = bh & 7;
    size_t qkb = (size_t)b * T_ * C_ + (size_t)h * D_;
    int m0 = blockIdx.x * 64, n0 = blockIdx.y * 64;
    int tid = threadIdx.x;
    int lr = tid >> 4, lc = tid & 15;
    float acc[4][4] = {};
    for (int k0 = 0; k0 < D_; k0 += 16) {
#pragma unroll
        for (int i = 0; i < 4; i++) {
            int row = lr + i * 16;
            int gm = m0 + row, gn = n0 + row;
            As2[lc][row] = (gm < T_) ? Q[qkb + (size_t)gm * C_ + k0 + lc] : 0.f;
            Bs2[lc][row] = (gn < T_) ? Kf[qkb + (size_t)gn * C_ + k0 + lc] : 0.f;
        }
        __syncthreads();
#pragma unroll
        for (int kk = 0; kk < 16; kk++) {
            float4 a4 = *(const float4*)&As2[kk][lr * 4];
            float4 b4 = *(const float4*)&Bs2[kk][lc * 4];
            float a0[4] = {a4.x, a4.y, a4.z, a4.w};
            float b0[4] = {b4.x, b4.y, b4.z, b4.w};
#pragma unroll
            for (int i = 0; i < 4; i++)
#pragma unroll
                for (int j = 0; j < 4; j++) acc[i][j] += a0[i] * b0[j];
        }
        __syncthreads();
    }
    const float scale = 0.14433756729740643f;
#pragma unroll
    for (int i = 0; i < 4; i++) {
        int m = m0 + lr * 4 + i;
        if (m >= T_) continue;
#pragma unroll
        for (int j = 0; j < 4; j++) {
            int n = n0 + lc * 4 + j;
            if (n < T_) S[((size_t)lbh * T_ + m) * T_ + n] = acc[i][j] * scale;
        }
    }
}

// ---------------- attention step 2: row softmax
__global__ __launch_bounds__(256) void softmax_kernel()
{
    float* S = ap<float>(S_OFF);
    int wave = threadIdx.x >> 6, lane = threadIdx.x & 63;
    size_t row = (size_t)blockIdx.x * 4 + wave;
    float* p = S + row * T_;
    float v[13];
    float m = -1e30f;
#pragma unroll
    for (int j = 0; j < 13; j++) {
        int idx = lane + 64 * j;
        v[j] = (idx < T_) ? p[idx] : -1e30f;
        m = fmaxf(m, v[j]);
    }
    for (int o = 32; o; o >>= 1) m = fmaxf(m, __shfl_down(m, o));
    m = __shfl(m, 0);
    float s = 0.f;
#pragma unroll
    for (int j = 0; j < 13; j++) { v[j] = expf(v[j] - m); s += v[j]; }
    for (int o = 32; o; o >>= 1) s += __shfl_down(s, o);
    s = __shfl(s, 0);
    float inv = 1.f / s;
#pragma unroll
    for (int j = 0; j < 13; j++) {
        int idx = lane + 64 * j;
        if (idx < T_) p[idx] = v[j] * inv;
    }
}

// ---------------- attention step 3: O = P V
__global__ __launch_bounds__(256) void gemm_pv(int bh0)
{
    __shared__ float As2[16][68];
    __shared__ float Bs[16][52];
    const float* S  = ap<float>(S_OFF);
    const float* Vf = ap<float>(V_OFF);
    float* A        = ap<float>(ATT_OFF);
    int lbh = blockIdx.y;
    int bh = bh0 + lbh;
    int b = bh >> 3, h = bh & 7;
    size_t vbase = (size_t)b * T_ * C_ + (size_t)h * D_;
    int m0 = blockIdx.x * 64;
    int tid = threadIdx.x;
    int lr = tid >> 4, lc = tid & 15;
    float acc[4][3] = {};
    for (int k0 = 0; k0 < T_; k0 += 16) {
#pragma unroll
        for (int i = 0; i < 4; i++) {
            int row = lr + i * 16;
            int gm = m0 + row, gk = k0 + lc;
            As2[lc][row] = (gm < T_ && gk < T_)
                ? S[((size_t)lbh * T_ + gm) * T_ + gk] : 0.f;
        }
        for (int e = tid; e < 768; e += 256) {
            int kk = e / 48, n = e - kk * 48;
            int gk = k0 + kk;
            Bs[kk][n] = (gk < T_) ? Vf[vbase + (size_t)gk * C_ + n] : 0.f;
        }
        __syncthreads();
#pragma unroll
        for (int kk = 0; kk < 16; kk++) {
            float4 a4 = *(const float4*)&As2[kk][lr * 4];
            float a0[4] = {a4.x, a4.y, a4.z, a4.w};
            float b0 = Bs[kk][lc * 3], b1 = Bs[kk][lc * 3 + 1], b2 = Bs[kk][lc * 3 + 2];
#pragma unroll
            for (int i = 0; i < 4; i++) {
                acc[i][0] += a0[i] * b0;
                acc[i][1] += a0[i] * b1;
                acc[i][2] += a0[i] * b2;
            }
        }
        __syncthreads();
    }
#pragma unroll
    for (int i = 0; i < 4; i++) {
        int m = m0 + lr * 4 + i;
        if (m >= T_) continue;
#pragma unroll
        for (int j = 0; j < 3; j++)
            A[vbase + (size_t)m * C_ + lc * 3 + j] = acc[i][j];
    }
}

// ---------------- ci stage A: partial column sums of XM (double)
__global__ __launch_bounds__(384) void cia_kernel()
{
    int b = blockIdx.x, s = blockIdx.y, c = threadIdx.x;
    const float* xm = ap<float>(XM_OFF);
    const int SL = (T_ + 7) / 8;
    int t0 = s * SL, t1 = min(t0 + SL, T_);
    double sm = 0.0;
    for (int t = t0; t < t1; t++) sm += (double)xm[((size_t)b * T_ + t) * C_ + c];
    ap<double>(CIP_OFF)[((size_t)b * 8 + s) * C_ + c] = sm;
}

// ---------------- ci stage B
__global__ __launch_bounds__(384) void cib_kernel()
{
    int b = blockIdx.x, c = threadIdx.x;
    const double* pp = ap<double>(CIP_OFF);
    double sm = 0.0;
#pragma unroll
    for (int s = 0; s < 8; s++) sm += pp[((size_t)b * 8 + s) * C_ + c];
    sm /= (double)T_;
    ap<double>(CID_OFF)[b * C_ + c] = 1.0 / (1.0 + exp(-sm));
}

// ---------------- ca[b][n] = dot(res1[b][n+1], ci[b])  (double)
__global__ __launch_bounds__(64) void ca_kernel()
{
    const float* xres1 = ap<float>(RES_OFF);
    const double* ci   = ap<double>(CID_OFF);
    int idx = blockIdx.x;
    int b = idx / HW_, n = idx - b * HW_;
    int lane = threadIdx.x;
    double s = 0.0;
    for (int c = lane; c < C_; c += 64)
        s += (double)xres1[((size_t)b * T_ + 1 + n) * C_ + c] * ci[b * C_ + c];
    for (int o = 32; o; o >>= 1) s += __shfl_down(s, o);
    if (lane == 0) ap<double>(CAD_OFF)[idx] = s;
}

// ---------------- stable ascending rank
__global__ __launch_bounds__(256) void rank_kernel()
{
    const double* ca = ap<double>(CAD_OFF);
    int* perm = ap<int>(PERM_OFF);
    int b = blockIdx.x, tid = threadIdx.x;
    __shared__ double cs[HW_];
    for (int i = tid; i < HW_; i += 256) cs[i] = ca[b * HW_ + i];
    __syncthreads();
    for (int i = tid; i < HW_; i += 256) {
        double vi = cs[i];
        int r = 0;
        for (int j = 0; j < HW_; j++) {
            double vj = cs[j];
            r += (vj < vi) || (vj == vi && j < i);
        }
        if (r >= HW_ - TP_ + 1) perm[b * (TP_ - 1) + (r - (HW_ - TP_ + 1))] = i;
    }
}

// ---------------- LN2 stage A: gathered partial stats (B x 8 blocks, fp64)
__global__ __launch_bounds__(256) void ln2a_kernel()
{
    const float* xres1 = ap<float>(RES_OFF);
    const int* perm = ap<int>(PERM_OFF);
    const int TC = TP_ * C_;            // 75,648
    const int SL = (TC + 7) / 8;        // 9,456
    int b = blockIdx.x, s = blockIdx.y, tid = threadIdx.x;
    int e0 = s * SL, e1 = min(e0 + SL, TC);
    __shared__ double r1[256], r2[256];
    double sm = 0.0, s2 = 0.0;
    for (int e = e0 + tid; e < e1; e += 256) {
        int t = e / C_, c = e - t * C_;
        int st = (t == 0) ? 0 : 1 + perm[b * (TP_ - 1) + t - 1];
        double v = (double)xres1[((size_t)b * T_ + st) * C_ + c];
        sm += v; s2 += v * v;
    }
    r1[tid] = sm; r2[tid] = s2; __syncthreads();
    for (int o = 128; o; o >>= 1) {
        if (tid < o) { r1[tid] += r1[tid + o]; r2[tid] += r2[tid + o]; }
        __syncthreads();
    }
    if (tid == 0) {
        double2* ps = ap<double2>(L2PS_OFF);
        ps[b * 8 + s] = make_double2(r1[0], r2[0]);
    }
}

// ---------------- LN2 stage B: finalize mu/rstd
__global__ __launch_bounds__(64) void ln2b_kernel()
{
    int b = blockIdx.x, lane = threadIdx.x;
    const double2* ps = ap<double2>(L2PS_OFF);
    double sm = 0.0, s2 = 0.0;
    if (lane < 8) { sm = ps[b * 8 + lane].x; s2 = ps[b * 8 + lane].y; }
    for (int o = 4; o; o >>= 1) { sm += __shfl_down(sm, o); s2 += __shfl_down(s2, o); }
    if (lane == 0) {
        const int TC = TP_ * C_;
        double m = sm / TC;
        double var = s2 / TC - m * m;
        ap<float>(L2MU_OFF)[b] = (float)m;
        ap<float>(L2RS_OFF)[b] = (float)(1.0 / sqrt(var + 1e-5));
    }
}

// ---------------- LN2 apply: gather + normalize -> X2N (parallel)
__global__ __launch_bounds__(256) void ln2_apply_kernel()
{
    size_t i = (size_t)blockIdx.x * 256 + threadIdx.x;
    if (i >= NX2) return;
    const int TC = TP_ * C_;
    int b = (int)(i / TC);
    int e = (int)(i - (size_t)b * TC);
    int t = e / C_, c = e - t * C_;
    const int* perm = ap<int>(PERM_OFF);
    int st = (t == 0) ? 0 : 1 + perm[b * (TP_ - 1) + t - 1];
    float v = ap<float>(RES_OFF)[((size_t)b * T_ + st) * C_ + c];
    ap<float>(X2N_OFF)[i] = (v - ap<float>(L2MU_OFF)[b]) * ap<float>(L2RS_OFF)[b]
                            * ap<float>(LN2W_OFF)[e] + ap<float>(LN2B_OFF)[e];
}

extern "C" void kernel_launch(void* const* d_in, const int* in_sizes, int n_in,
                              void* d_out, int out_size, void* d_ws, size_t ws_size,
                              hipStream_t stream)
{
    float* out = (float*)d_out;
    (void)d_ws; (void)ws_size; (void)in_sizes; (void)n_in; (void)out_size;

    const int M1 = B_ * T_;          // 25120
    const int M2 = B_ * TP_;         // 6304
    const int GM1 = (M1 + 63) / 64;  // 393
    const int GM2 = (M2 + 63) / 64;  // 99
    const int GT  = (T_ + 63) / 64;  // 13

    // 0. dtype detect + merged fp32 conversion
    detect_kernel<<<1, 64, 0, stream>>>((const unsigned*)d_in[2]);
    SrcPtrs sp;
    for (int i = 0; i < 12; i++) sp.p[i] = d_in[i];
    cvt_all_kernel<<<(int)((NTOT_CVT + 255) / 256), 256, 0, stream>>>(sp);

    // 1. LN1
    stats1a_kernel<<<dim3(B_, 16), 256, 0, stream>>>();
    stats1b_kernel<<<B_, 64, 0, stream>>>();
    ln1_apply_kernel<<<(int)((NRES + 255) / 256), 256, 0, stream>>>();

    // 2. QKV projections
    gemm_t<0><<<dim3(GM1, C_ / 64), 256, 0, stream>>>(X1_OFF, WQF_OFF, nullptr, Q_OFF, M1, C_, C_);
    gemm_t<0><<<dim3(GM1, C_ / 64), 256, 0, stream>>>(X1_OFF, WKF_OFF, nullptr, K_OFF, M1, C_, C_);
    gemm_t<0><<<dim3(GM1, C_ / 64), 256, 0, stream>>>(X1_OFF, WVF_OFF, nullptr, V_OFF, M1, C_, C_);

    // 3. attention (batched GEMMs, CH_ heads per chunk)
    for (int bh0 = 0; bh0 < B_ * H_; bh0 += CH_) {
        gemm_s<<<dim3(GT, GT, CH_), 256, 0, stream>>>(bh0);
        softmax_kernel<<<CH_ * T_ / 4 + (CH_ * T_ % 4 ? 1 : 0), 256, 0, stream>>>();
        gemm_pv<<<dim3(GT, CH_), 256, 0, stream>>>(bh0);
    }
    // Wo projection fused with residual
    gemm_t<4><<<dim3(GM1, C_ / 64), 256, 0, stream>>>(ATT_OFF, WOF_OFF, nullptr, XM_OFF, M1, C_, C_);

    // 4. ci, ca, rank, LN2 (all multi-block now)
    cia_kernel<<<dim3(B_, 8), 384, 0, stream>>>();
    cib_kernel<<<B_, 384, 0, stream>>>();
    ca_kernel<<<B_ * HW_, 64, 0, stream>>>();
    rank_kernel<<<B_, 256, 0, stream>>>();
    ln2a_kernel<<<dim3(B_, 8), 256, 0, stream>>>();
    ln2b_kernel<<<B_, 64, 0, stream>>>();
    ln2_apply_kernel<<<(int)((NX2 + 255) / 256), 256, 0, stream>>>();

    // 5. FFN
    gemm_t<2><<<dim3(GM2, FF_ / 64), 256, 0, stream>>>(X2N_OFF, W1F_OFF, nullptr, H_OFF, M2, FF_, C_);
    gemm_t<3><<<dim3(GM2, C_ / 64), 256, 0, stream>>>(H_OFF, W2F_OFF, out, 0, M2, C_, FF_);
}